// Round 7
// baseline (141.142 us; speedup 1.0000x reference)
//
#include <hip/hip_runtime.h>
#include <hip/hip_bf16.h>

#define NN 2000
#define DD 24
#define JA 576
#define GROW 160              // per-(g,l) row: 144 (2*beta) + 6 alpha + 6 (2*diag) + 4 pad
#define GA_OFF 144
#define GD_OFF 150
#define IDXCAP 2048           // >= NN, rows can never overflow
#define THRESH 16.0f          // keep pair if S - max_j diff_j^2 <= THRESH
#define PREP_BLOCKS 320       // 32 x 10
#define SPLIT 32              // list split factor (grid y of passB)

// ================= merged prep (Wg build) + passA (survivor lists) =================
// Wg[g][l][160]: [q*24+a] = 2*beta[6g+q][a][l]; [144+q] = alpha[6g+q][l];
//                [150+q] = 2*beta[j][j][l], j=6g+q.
// Survivor predicate is symmetric in (i,l) => row[i] = ascending partner list of i.
__global__ __launch_bounds__(256) void k_prepA(const float* __restrict__ beta,
                                               const float* __restrict__ alpha,
                                               const float* __restrict__ x,
                                               float* __restrict__ Wg,
                                               int* __restrict__ cnt,
                                               unsigned short* __restrict__ idx) {
    const int tid = threadIdx.x;
    if (blockIdx.x < PREP_BLOCKS) {
        const int xb = blockIdx.x & 31, yb = blockIdx.x >> 5;   // 32 x 10
        const int tx = tid & 63, ty = tid >> 6;
        if (yb < 9) {
            __shared__ float t[64][65];
            const int l0 = xb * 64, ja0 = yb * 64;
            for (int r = ty; r < 64; r += 4) {
                int ja = ja0 + r, l = l0 + tx;
                if (ja < JA && l < NN) t[r][tx] = 2.0f * beta[(size_t)ja * NN + l];
            }
            __syncthreads();
            for (int r = ty; r < 64; r += 4) {
                int l = l0 + r, ja = ja0 + tx;
                if (l < NN && ja < JA) {
                    int g = ja / 144, pos = ja % 144;
                    Wg[((size_t)g * NN + l) * GROW + pos] = t[tx][r];
                }
            }
        } else {
            int l = xb * 64 + (tid & 63);
            int g = tid >> 6;                 // 0..3
            if (l < NN) {
                float* w = Wg + ((size_t)g * NN + l) * GROW;
                #pragma unroll
                for (int q = 0; q < 6; ++q) {
                    int j = g * 6 + q;
                    w[GA_OFF + q] = alpha[(size_t)j * NN + l];
                    w[GD_OFF + q] = 2.0f * beta[(size_t)(j * DD + j) * NN + l];
                }
            }
        }
    } else {
        const int pa = blockIdx.x - PREP_BLOCKS;       // 0..499
        const int wave = tid >> 6, lane = tid & 63;
        const int l = pa * 4 + wave;                   // 0..1999 (row owner)
        float xl[DD];
        {
            const float* xr = x + (size_t)l * DD;
            #pragma unroll
            for (int k = 0; k < DD; ++k) xl[k] = xr[k];
        }
        unsigned short* row = idx + (size_t)l * IDXCAP;
        int base = 0;
        for (int c = 0; c < 32; ++c) {
            int i = c * 64 + lane;
            bool valid = i < NN;
            int ic = valid ? i : 0;
            const float4* xv = reinterpret_cast<const float4*>(x + (size_t)ic * DD);
            float S = 0.f, m2 = 0.f;
            #pragma unroll
            for (int q = 0; q < 6; ++q) {
                float4 v = xv[q];
                float d0 = v.x - xl[4*q+0], d1 = v.y - xl[4*q+1];
                float d2 = v.z - xl[4*q+2], d3 = v.w - xl[4*q+3];
                d0 *= d0; d1 *= d1; d2 *= d2; d3 *= d3;
                S += (d0 + d1) + (d2 + d3);
                m2 = fmaxf(m2, fmaxf(fmaxf(d0, d1), fmaxf(d2, d3)));
            }
            bool pred = valid && (S - m2 <= THRESH);
            unsigned long long mask = __ballot(pred);
            if (pred) {
                int rank = __popcll(mask & ((1ull << lane) - 1ull));
                row[base + rank] = (unsigned short)i;
            }
            base += __popcll(mask);
        }
        if (lane == 0) cnt[l] = base;
    }
}

// ================= pass B: per-thread register accumulation over per-i lists ==========
// Thread (i=lane+64*bx, jgroup=wave, y=by): entries e = by, by+SPLIT, ... of row[i].
// No barriers, no shared accumulators, bit-deterministic (fixed order per thread).
template <int J0>
__device__ __forceinline__ void passB_body(const float* __restrict__ x,
                                           const float* __restrict__ Wg,
                                           const int* __restrict__ cnt,
                                           const unsigned short* __restrict__ idx,
                                           float* __restrict__ part,
                                           int i, int by) {
    constexpr int g = J0 / 6;
    const int ic = i < NN ? i : 0;

    float xi[DD];
    {
        const float4* xr = reinterpret_cast<const float4*>(x + (size_t)ic * DD);
        #pragma unroll
        for (int q = 0; q < 6; ++q) {
            float4 v = xr[q];
            xi[4*q+0] = v.x; xi[4*q+1] = v.y; xi[4*q+2] = v.z; xi[4*q+3] = v.w;
        }
    }

    const int c = (i < NN) ? cnt[i] : 0;
    const unsigned short* row = idx + (size_t)i * IDXCAP;

    float acc[6];
    #pragma unroll
    for (int q = 0; q < 6; ++q) acc[q] = 0.0f;

    #pragma unroll 1
    for (int e = by; e < c; e += SPLIT) {
        const int l = row[e];
        const float* __restrict__ wrow = Wg + ((size_t)g * NN + l) * GROW;
        const float4* __restrict__ wv  = reinterpret_cast<const float4*>(wrow);
        const float4* __restrict__ xv  = reinterpret_cast<const float4*>(x + (size_t)l * DD);

        float diff[DD];
        float negS = 0.f;
        #pragma unroll
        for (int q = 0; q < 6; ++q) {
            float4 vv = xv[q];
            float d0 = xi[4*q+0] - vv.x, d1 = xi[4*q+1] - vv.y;
            float d2 = xi[4*q+2] - vv.z, d3 = xi[4*q+3] - vv.w;
            diff[4*q+0] = d0; diff[4*q+1] = d1;
            diff[4*q+2] = d2; diff[4*q+3] = d3;
            negS = fmaf(-d0, d0, negS); negS = fmaf(-d1, d1, negS);
            negS = fmaf(-d2, d2, negS); negS = fmaf(-d3, d3, negS);
        }

        #pragma unroll
        for (int q = 0; q < 6; ++q) {
            float dj = diff[J0 % 6 == 0 ? (J0 + q) : (J0 + q)];  // compile-time J0+q
            float K = __expf(fmaf(dj, dj, negS));                // exp(diff_j^2 - S)
            const float4* bq = wv + q * 6;                       // 24 floats of 2*beta[j][*]
            float t0 = 0.f, t1 = 0.f, t2 = 0.f, t3 = 0.f;
            #pragma unroll
            for (int a4 = 0; a4 < 6; ++a4) {
                float4 b = bq[a4];
                t0 = fmaf(b.x, diff[4*a4+0], t0);
                t1 = fmaf(b.y, diff[4*a4+1], t1);
                t2 = fmaf(b.z, diff[4*a4+2], t2);
                t3 = fmaf(b.w, diff[4*a4+3], t3);
            }
            float t = (t0 + t1) + (t2 + t3);
            t = fmaf(-wrow[GD_OFF + q], dj, t);                  // drop a==j
            acc[q] += K * (wrow[GA_OFF + q] + t);
        }
    }

    if (i < NN) {
        float* p = part + ((size_t)(by * 4 + g) * NN + i) * 6;
        #pragma unroll
        for (int q = 0; q < 6; ++q) p[q] = acc[q];
    }
}

__global__ __launch_bounds__(256, 4) void k_passB(const float* __restrict__ x,
                                                  const float* __restrict__ Wg,
                                                  const int* __restrict__ cnt,
                                                  const unsigned short* __restrict__ idx,
                                                  float* __restrict__ part) {
    const int tid = threadIdx.x;
    const int wave = tid >> 6, lane = tid & 63;
    const int i = blockIdx.x * 64 + lane;     // 0..2047 (guarded)
    const int by = blockIdx.y;                // 0..SPLIT-1
    if      (wave == 0) passB_body<0 >(x, Wg, cnt, idx, part, i, by);
    else if (wave == 1) passB_body<6 >(x, Wg, cnt, idx, part, i, by);
    else if (wave == 2) passB_body<12>(x, Wg, cnt, idx, part, i, by);
    else                passB_body<18>(x, Wg, cnt, idx, part, i, by);
}

// ---- pass C: out[i][j] = sum_y part[(y*4 + j/6)][i][j%6]
__global__ __launch_bounds__(256) void k_passC(const float* __restrict__ part,
                                               float* __restrict__ out) {
    int m = blockIdx.x * 256 + threadIdx.x;
    if (m >= NN * DD) return;
    int i = m / DD, j = m - i * DD;
    int g = j / 6, q = j - g * 6;
    const float* p = part + ((size_t)g * NN + i) * 6 + q;
    float acc = 0.f;
    #pragma unroll 8
    for (int y = 0; y < SPLIT; ++y)
        acc += p[(size_t)y * 4 * NN * 6];
    out[m] = acc;
}

// ================= dense fallback (round-4 structure, Wg layout) =================
template <int J0>
__device__ __forceinline__ void run_j6(const float* __restrict__ x,
                                       const float* __restrict__ Wg,
                                       float* __restrict__ part,
                                       const float (&xi)[DD],
                                       int i, int lb, int l0, int l1) {
    constexpr int g = J0 / 6;
    float acc[6];
    #pragma unroll
    for (int q = 0; q < 6; ++q) acc[q] = 0.0f;
    #pragma unroll 1
    for (int l = l0; l < l1; ++l) {
        const float* __restrict__ wrow = Wg + ((size_t)g * NN + l) * GROW;
        const float* __restrict__ xl = x + (size_t)l * DD;
        float diff[DD]; float negS = 0.0f;
        #pragma unroll
        for (int k = 0; k < DD; ++k) {
            float d = xi[k] - xl[k];
            diff[k] = d; negS = fmaf(-d, d, negS);
        }
        #pragma unroll
        for (int q = 0; q < 6; ++q) {
            float dj = diff[J0 + q];
            float K = __expf(fmaf(dj, dj, negS));
            const float* bj = wrow + q * DD;
            float t0=0.f,t1=0.f,t2=0.f,t3=0.f;
            #pragma unroll
            for (int a = 0; a < DD; a += 4) {
                t0 = fmaf(bj[a+0], diff[a+0], t0);
                t1 = fmaf(bj[a+1], diff[a+1], t1);
                t2 = fmaf(bj[a+2], diff[a+2], t2);
                t3 = fmaf(bj[a+3], diff[a+3], t3);
            }
            float t = (t0+t1)+(t2+t3);
            t = fmaf(-wrow[GD_OFF + q], dj, t);
            acc[q] = fmaf(K, wrow[GA_OFF + q] + t, acc[q]);
        }
    }
    if (i < NN) {
        #pragma unroll
        for (int q = 0; q < 6; ++q)
            part[((size_t)lb * DD + (J0+q)) * NN + i] = acc[q];
    }
}

__global__ __launch_bounds__(256, 4) void k_pass1_js(const float* __restrict__ x,
                                                     const float* __restrict__ Wg,
                                                     float* __restrict__ part,
                                                     int lch) {
    const int tid  = threadIdx.x;
    const int wave = tid >> 6, lane = tid & 63;
    const int i  = blockIdx.x * 64 + lane;
    const int ic = i < NN ? i : NN - 1;
    const int lb = blockIdx.y;
    float xi[DD];
    {
        const float4* xr = reinterpret_cast<const float4*>(x + (size_t)ic * DD);
        #pragma unroll
        for (int q = 0; q < DD/4; ++q) {
            float4 v = xr[q];
            xi[4*q+0]=v.x; xi[4*q+1]=v.y; xi[4*q+2]=v.z; xi[4*q+3]=v.w;
        }
    }
    const int l0 = lb * lch;
    int l1 = l0 + lch; if (l1 > NN) l1 = NN;
    if      (wave == 0) run_j6<0 >(x, Wg, part, xi, i, lb, l0, l1);
    else if (wave == 1) run_j6<6 >(x, Wg, part, xi, i, lb, l0, l1);
    else if (wave == 2) run_j6<12>(x, Wg, part, xi, i, lb, l0, l1);
    else                run_j6<18>(x, Wg, part, xi, i, lb, l0, l1);
}

__global__ __launch_bounds__(256) void k_pass2t(const float* __restrict__ part,
                                                float* __restrict__ out, int lblk) {
    int m = blockIdx.x * 256 + threadIdx.x;
    if (m >= NN * DD) return;
    float s = 0.0f;
    for (int b = 0; b < lblk; ++b)
        s += part[(size_t)b * (NN * DD) + m];
    int j = m / NN, i = m - j * NN;
    out[(size_t)i * DD + j] = s;
}
// ================= end fallback =================

extern "C" void kernel_launch(void* const* d_in, const int* in_sizes, int n_in,
                              void* d_out, int out_size, void* d_ws, size_t ws_size,
                              hipStream_t stream) {
    const float* x     = (const float*)d_in[0];   // [2000, 24]
    const float* alpha = (const float*)d_in[1];   // [24, 2000]
    const float* beta  = (const float*)d_in[2];   // [24, 24, 2000]
    float* out = (float*)d_out;                   // [2000, 24]

    const size_t WBYTES    = (size_t)4 * NN * GROW * 4;            // 5,120,000
    const size_t CNT_OFF   = WBYTES;
    const size_t IDX_OFF   = CNT_OFF + 8192;
    const size_t IDXBYTES  = (size_t)NN * IDXCAP * 2;              // 8,192,000
    const size_t PART_OFF  = IDX_OFF + IDXBYTES;
    const size_t PARTBYTES = (size_t)SPLIT * 4 * NN * 6 * 4;       // 6,144,000
    const size_t NEED = PART_OFF + PARTBYTES;                      // ~19.5 MB

    float* Wg = (float*)d_ws;

    if (ws_size >= NEED) {
        int* cnt = (int*)((char*)d_ws + CNT_OFF);
        unsigned short* idx = (unsigned short*)((char*)d_ws + IDX_OFF);
        float* part = (float*)((char*)d_ws + PART_OFF);

        k_prepA<<<PREP_BLOCKS + 500, 256, 0, stream>>>(beta, alpha, x, Wg, cnt, idx);
        k_passB<<<dim3(32, SPLIT), 256, 0, stream>>>(x, Wg, cnt, idx, part);
        k_passC<<<(NN * DD + 255) / 256, 256, 0, stream>>>(part, out);
    } else {
        // dense fallback (unlikely: ws proven >= 37 MB in earlier rounds)
        const size_t SLAB = (size_t)NN * DD * 4;
        float* part = (float*)((char*)d_ws + WBYTES);
        int lblk = 64;
        while (lblk > 1 && WBYTES + (size_t)lblk * SLAB > ws_size) lblk >>= 1;
        int lch = (NN + lblk - 1) / lblk;
        // build Wg via prep-only blocks of k_prepA? use full k_prepA with dummy lists:
        int* cnt = (int*)((char*)d_ws + CNT_OFF);
        unsigned short* idx = (unsigned short*)((char*)d_ws + CNT_OFF + 8192);
        if (ws_size >= IDX_OFF + IDXBYTES) {
            k_prepA<<<PREP_BLOCKS + 500, 256, 0, stream>>>(beta, alpha, x, Wg, cnt, idx);
        } else {
            k_prepA<<<PREP_BLOCKS, 256, 0, stream>>>(beta, alpha, x, Wg, cnt, idx);
        }
        k_pass1_js<<<dim3(32, lblk), 256, 0, stream>>>(x, Wg, part, lch);
        k_pass2t<<<(NN * DD + 255) / 256, 256, 0, stream>>>(part, out, lblk);
    }
}

// Round 8
// 87.237 us; speedup vs baseline: 1.6179x; 1.6179x over previous
//
#include <hip/hip_runtime.h>
#include <hip/hip_bf16.h>

#define NN 2000
#define DD 24
#define JA 576
#define GROW 160              // per-(g,l) row: 144 (2*beta) + 6 alpha + 6 (2*diag) + 4 pad
#define GA_OFF 144
#define GD_OFF 150
#define IDXCAP 2048           // >= NN, rows can never overflow
#define THRESH 16.0f          // keep pair if S - max_j diff_j^2 <= THRESH
#define PREP_BLOCKS 320       // 32 x 10
#define NS 16                 // l-slabs of 128 (16*128 = 2048 >= NN)

// ================= merged prep (Wg build) + passA (survivor lists + slab offsets) =====
// Wg[g][l][160]: [q*24+a] = 2*beta[6g+q][a][l]; [144+q] = alpha[6g+q][l];
//                [150+q] = 2*beta[j][j][l], j=6g+q.
// Survivor predicate is symmetric in (i,l) => row[i] = ascending partner list of i.
// off[s][i] = #entries of row[i] with partner < 128*s  (s in [0,16]); off[16][i]=count.
__global__ __launch_bounds__(256) void k_prepA(const float* __restrict__ beta,
                                               const float* __restrict__ alpha,
                                               const float* __restrict__ x,
                                               float* __restrict__ Wg,
                                               int* __restrict__ off,
                                               unsigned short* __restrict__ idx) {
    const int tid = threadIdx.x;
    if (blockIdx.x < PREP_BLOCKS) {
        const int xb = blockIdx.x & 31, yb = blockIdx.x >> 5;   // 32 x 10
        const int tx = tid & 63, ty = tid >> 6;
        if (yb < 9) {
            __shared__ float t[64][65];
            const int l0 = xb * 64, ja0 = yb * 64;
            for (int r = ty; r < 64; r += 4) {
                int ja = ja0 + r, l = l0 + tx;
                if (ja < JA && l < NN) t[r][tx] = 2.0f * beta[(size_t)ja * NN + l];
            }
            __syncthreads();
            for (int r = ty; r < 64; r += 4) {
                int l = l0 + r, ja = ja0 + tx;
                if (l < NN && ja < JA) {
                    int g = ja / 144, pos = ja % 144;
                    Wg[((size_t)g * NN + l) * GROW + pos] = t[tx][r];
                }
            }
        } else {
            int l = xb * 64 + (tid & 63);
            int g = tid >> 6;                 // 0..3
            if (l < NN) {
                float* w = Wg + ((size_t)g * NN + l) * GROW;
                #pragma unroll
                for (int q = 0; q < 6; ++q) {
                    int j = g * 6 + q;
                    w[GA_OFF + q] = alpha[(size_t)j * NN + l];
                    w[GD_OFF + q] = 2.0f * beta[(size_t)(j * DD + j) * NN + l];
                }
            }
        }
    } else {
        const int pa = blockIdx.x - PREP_BLOCKS;       // 0..499
        const int wave = tid >> 6, lane = tid & 63;
        const int l = pa * 4 + wave;                   // 0..1999 (row owner)
        float xl[DD];
        {
            const float* xr = x + (size_t)l * DD;
            #pragma unroll
            for (int k = 0; k < DD; ++k) xl[k] = xr[k];
        }
        unsigned short* row = idx + (size_t)l * IDXCAP;
        int base = 0;
        for (int c = 0; c < 32; ++c) {
            if ((c & 1) == 0 && lane == 0)
                off[(size_t)(c >> 1) * NN + l] = base;     // slab s = c/2 starts here
            int i = c * 64 + lane;
            bool valid = i < NN;
            int ic = valid ? i : 0;
            const float4* xv = reinterpret_cast<const float4*>(x + (size_t)ic * DD);
            float S = 0.f, m2 = 0.f;
            #pragma unroll
            for (int q = 0; q < 6; ++q) {
                float4 v = xv[q];
                float d0 = v.x - xl[4*q+0], d1 = v.y - xl[4*q+1];
                float d2 = v.z - xl[4*q+2], d3 = v.w - xl[4*q+3];
                d0 *= d0; d1 *= d1; d2 *= d2; d3 *= d3;
                S += (d0 + d1) + (d2 + d3);
                m2 = fmaxf(m2, fmaxf(fmaxf(d0, d1), fmaxf(d2, d3)));
            }
            bool pred = valid && (S - m2 <= THRESH);
            unsigned long long mask = __ballot(pred);
            if (pred) {
                int rank = __popcll(mask & ((1ull << lane) - 1ull));
                row[base + rank] = (unsigned short)i;
            }
            base += __popcll(mask);
        }
        if (lane == 0) off[(size_t)16 * NN + l] = base;
    }
}

// ================= pass B: i-major register accumulation, l-slab-blocked =============
// Block (ib, s, g): thread i = ib*256+tid accumulates entries of row[i] with
// l in slab s (contiguous range off[s][i]..off[s+1][i]). No barriers, no RMW,
// bit-deterministic (ascending e per thread). s in low grid bits -> each XCD's
// round-robin share touches ~2 slabs of Wg (~650 KB) -> L2-resident.
template <int J0>
__device__ __forceinline__ void passB_body(const float* __restrict__ x,
                                           const float* __restrict__ Wg,
                                           const int* __restrict__ off,
                                           const unsigned short* __restrict__ idx,
                                           float* __restrict__ part,
                                           int i, int s) {
    constexpr int g = J0 / 6;
    const int ic = i < NN ? i : 0;

    float xi[DD];
    {
        const float4* xr = reinterpret_cast<const float4*>(x + (size_t)ic * DD);
        #pragma unroll
        for (int q = 0; q < 6; ++q) {
            float4 v = xr[q];
            xi[4*q+0] = v.x; xi[4*q+1] = v.y; xi[4*q+2] = v.z; xi[4*q+3] = v.w;
        }
    }

    int e0 = 0, e1 = 0;
    if (i < NN) {
        e0 = off[(size_t)s * NN + i];
        e1 = off[(size_t)(s + 1) * NN + i];
    }
    const unsigned short* row = idx + (size_t)i * IDXCAP;

    float acc[6];
    #pragma unroll
    for (int q = 0; q < 6; ++q) acc[q] = 0.0f;

    #pragma unroll 1
    for (int e = e0; e < e1; ++e) {
        const int l = row[e];
        const float* __restrict__ wrow = Wg + ((size_t)g * NN + l) * GROW;
        const float4* __restrict__ wv  = reinterpret_cast<const float4*>(wrow);
        const float4* __restrict__ xv  = reinterpret_cast<const float4*>(x + (size_t)l * DD);

        float diff[DD];
        float negS = 0.f;
        #pragma unroll
        for (int q = 0; q < 6; ++q) {
            float4 vv = xv[q];
            float d0 = xi[4*q+0] - vv.x, d1 = xi[4*q+1] - vv.y;
            float d2 = xi[4*q+2] - vv.z, d3 = xi[4*q+3] - vv.w;
            diff[4*q+0] = d0; diff[4*q+1] = d1;
            diff[4*q+2] = d2; diff[4*q+3] = d3;
            negS = fmaf(-d0, d0, negS); negS = fmaf(-d1, d1, negS);
            negS = fmaf(-d2, d2, negS); negS = fmaf(-d3, d3, negS);
        }

        #pragma unroll
        for (int q = 0; q < 6; ++q) {
            float dj = diff[J0 + q];                         // compile-time index
            float K = __expf(fmaf(dj, dj, negS));            // exp(diff_j^2 - S)
            const float4* bq = wv + q * 6;                   // 24 floats of 2*beta[j][*]
            float t0 = 0.f, t1 = 0.f, t2 = 0.f, t3 = 0.f;
            #pragma unroll
            for (int a4 = 0; a4 < 6; ++a4) {
                float4 b = bq[a4];
                t0 = fmaf(b.x, diff[4*a4+0], t0);
                t1 = fmaf(b.y, diff[4*a4+1], t1);
                t2 = fmaf(b.z, diff[4*a4+2], t2);
                t3 = fmaf(b.w, diff[4*a4+3], t3);
            }
            float t = (t0 + t1) + (t2 + t3);
            t = fmaf(-wrow[GD_OFF + q], dj, t);              // drop a==j
            acc[q] += K * (wrow[GA_OFF + q] + t);
        }
    }

    if (i < NN) {
        float* p = part + ((size_t)(s * 4 + g) * NN + i) * 6;
        #pragma unroll
        for (int q = 0; q < 6; ++q) p[q] = acc[q];
    }
}

__global__ __launch_bounds__(256) void k_passB(const float* __restrict__ x,
                                               const float* __restrict__ Wg,
                                               const int* __restrict__ off,
                                               const unsigned short* __restrict__ idx,
                                               float* __restrict__ part) {
    const int bid = blockIdx.x;                // 512 blocks
    const int s  = bid & 15;                   // slab in low bits -> XCD locality
    const int g  = (bid >> 4) & 3;
    const int ib = bid >> 6;                   // 0..7
    const int i  = ib * 256 + threadIdx.x;     // 0..2047 (guarded)
    switch (g) {
        case 0:  passB_body<0 >(x, Wg, off, idx, part, i, s); break;
        case 1:  passB_body<6 >(x, Wg, off, idx, part, i, s); break;
        case 2:  passB_body<12>(x, Wg, off, idx, part, i, s); break;
        default: passB_body<18>(x, Wg, off, idx, part, i, s); break;
    }
}

// ---- pass C: out[i][j] = sum_s part[(s*4 + j/6)][i][j%6]
__global__ __launch_bounds__(256) void k_passC(const float* __restrict__ part,
                                               float* __restrict__ out) {
    int m = blockIdx.x * 256 + threadIdx.x;
    if (m >= NN * DD) return;
    int i = m / DD, j = m - i * DD;
    int g = j / 6, q = j - g * 6;
    float a = 0.f;
    #pragma unroll
    for (int s = 0; s < NS; ++s)
        a += part[((size_t)(s * 4 + g) * NN + i) * 6 + q];
    out[m] = a;
}

// ================= dense fallback (round-4 structure, Wg layout) =================
template <int J0>
__device__ __forceinline__ void run_j6(const float* __restrict__ x,
                                       const float* __restrict__ Wg,
                                       float* __restrict__ part,
                                       const float (&xi)[DD],
                                       int i, int lb, int l0, int l1) {
    constexpr int g = J0 / 6;
    float acc[6];
    #pragma unroll
    for (int q = 0; q < 6; ++q) acc[q] = 0.0f;
    #pragma unroll 1
    for (int l = l0; l < l1; ++l) {
        const float* __restrict__ wrow = Wg + ((size_t)g * NN + l) * GROW;
        const float* __restrict__ xl = x + (size_t)l * DD;
        float diff[DD]; float negS = 0.0f;
        #pragma unroll
        for (int k = 0; k < DD; ++k) {
            float d = xi[k] - xl[k];
            diff[k] = d; negS = fmaf(-d, d, negS);
        }
        #pragma unroll
        for (int q = 0; q < 6; ++q) {
            float dj = diff[J0 + q];
            float K = __expf(fmaf(dj, dj, negS));
            const float* bj = wrow + q * DD;
            float t0=0.f,t1=0.f,t2=0.f,t3=0.f;
            #pragma unroll
            for (int a = 0; a < DD; a += 4) {
                t0 = fmaf(bj[a+0], diff[a+0], t0);
                t1 = fmaf(bj[a+1], diff[a+1], t1);
                t2 = fmaf(bj[a+2], diff[a+2], t2);
                t3 = fmaf(bj[a+3], diff[a+3], t3);
            }
            float t = (t0+t1)+(t2+t3);
            t = fmaf(-wrow[GD_OFF + q], dj, t);
            acc[q] = fmaf(K, wrow[GA_OFF + q] + t, acc[q]);
        }
    }
    if (i < NN) {
        #pragma unroll
        for (int q = 0; q < 6; ++q)
            part[((size_t)lb * DD + (J0+q)) * NN + i] = acc[q];
    }
}

__global__ __launch_bounds__(256, 4) void k_pass1_js(const float* __restrict__ x,
                                                     const float* __restrict__ Wg,
                                                     float* __restrict__ part,
                                                     int lch) {
    const int tid  = threadIdx.x;
    const int wave = tid >> 6, lane = tid & 63;
    const int i  = blockIdx.x * 64 + lane;
    const int ic = i < NN ? i : NN - 1;
    const int lb = blockIdx.y;
    float xi[DD];
    {
        const float4* xr = reinterpret_cast<const float4*>(x + (size_t)ic * DD);
        #pragma unroll
        for (int q = 0; q < DD/4; ++q) {
            float4 v = xr[q];
            xi[4*q+0]=v.x; xi[4*q+1]=v.y; xi[4*q+2]=v.z; xi[4*q+3]=v.w;
        }
    }
    const int l0 = lb * lch;
    int l1 = l0 + lch; if (l1 > NN) l1 = NN;
    if      (wave == 0) run_j6<0 >(x, Wg, part, xi, i, lb, l0, l1);
    else if (wave == 1) run_j6<6 >(x, Wg, part, xi, i, lb, l0, l1);
    else if (wave == 2) run_j6<12>(x, Wg, part, xi, i, lb, l0, l1);
    else                run_j6<18>(x, Wg, part, xi, i, lb, l0, l1);
}

__global__ __launch_bounds__(256) void k_pass2t(const float* __restrict__ part,
                                                float* __restrict__ out, int lblk) {
    int m = blockIdx.x * 256 + threadIdx.x;
    if (m >= NN * DD) return;
    float s = 0.0f;
    for (int b = 0; b < lblk; ++b)
        s += part[(size_t)b * (NN * DD) + m];
    int j = m / NN, i = m - j * NN;
    out[(size_t)i * DD + j] = s;
}
// ================= end fallback =================

extern "C" void kernel_launch(void* const* d_in, const int* in_sizes, int n_in,
                              void* d_out, int out_size, void* d_ws, size_t ws_size,
                              hipStream_t stream) {
    const float* x     = (const float*)d_in[0];   // [2000, 24]
    const float* alpha = (const float*)d_in[1];   // [24, 2000]
    const float* beta  = (const float*)d_in[2];   // [24, 24, 2000]
    float* out = (float*)d_out;                   // [2000, 24]

    const size_t WBYTES    = (size_t)4 * NN * GROW * 4;            // 5,120,000
    const size_t OFF_OFF   = WBYTES;
    const size_t OFFBYTES  = (size_t)17 * NN * 4;                  // 136,000
    const size_t IDX_OFF   = OFF_OFF + OFFBYTES;                   // 5,256,000
    const size_t IDXBYTES  = (size_t)NN * IDXCAP * 2;              // 8,192,000
    const size_t PART_OFF  = IDX_OFF + IDXBYTES;                   // 13,448,000
    const size_t PARTBYTES = (size_t)NS * 4 * NN * 6 * 4;          // 3,072,000
    const size_t NEED = PART_OFF + PARTBYTES;                      // ~16.5 MB

    float* Wg = (float*)d_ws;

    if (ws_size >= NEED) {
        int* off = (int*)((char*)d_ws + OFF_OFF);
        unsigned short* idx = (unsigned short*)((char*)d_ws + IDX_OFF);
        float* part = (float*)((char*)d_ws + PART_OFF);

        k_prepA<<<PREP_BLOCKS + 500, 256, 0, stream>>>(beta, alpha, x, Wg, off, idx);
        k_passB<<<8 * NS * 4, 256, 0, stream>>>(x, Wg, off, idx, part);
        k_passC<<<(NN * DD + 255) / 256, 256, 0, stream>>>(part, out);
    } else {
        // dense fallback (unlikely: ws proven >= 53 MB in earlier rounds)
        const size_t SLAB = (size_t)NN * DD * 4;
        float* part = (float*)((char*)d_ws + WBYTES);
        int lblk = 64;
        while (lblk > 1 && WBYTES + (size_t)lblk * SLAB > ws_size) lblk >>= 1;
        int lch = (NN + lblk - 1) / lblk;
        int* off = (int*)((char*)d_ws + WBYTES);   // untouched by prep-only blocks
        unsigned short* idx = (unsigned short*)((char*)d_ws + WBYTES);
        k_prepA<<<PREP_BLOCKS, 256, 0, stream>>>(beta, alpha, x, Wg, off, idx);
        k_pass1_js<<<dim3(32, lblk), 256, 0, stream>>>(x, Wg, part, lch);
        k_pass2t<<<(NN * DD + 255) / 256, 256, 0, stream>>>(part, out, lblk);
    }
}

// Round 9
// 67.470 us; speedup vs baseline: 2.0919x; 1.2930x over previous
//
#include <hip/hip_runtime.h>
#include <hip/hip_bf16.h>
#include <hip/hip_fp16.h>

#define NN 2000
#define DD 24
#define JA 576
#define GROWH 160             // halves per (g,l) row: 144 (2*beta) + 6 alpha + 6 (2*diag) + 4 pad
#define HA_OFF 144
#define HD_OFF 150
#define IDXCAP 2048           // >= NN, rows can never overflow
#define THRESH 16.0f          // keep pair if S - max_j diff_j^2 <= THRESH
#define PREP_BLOCKS 320       // 32 x 10
#define NS 32                 // l-slabs of 64 (32*64 = 2048 >= NN)

// ================= merged prep (fp16 Wg build) + passA (survivor lists + slab offsets) ===
// Wg[g][l][160h]: [q*24+a] = 2*beta[6g+q][a][l] (fp16); [144+q] = alpha; [150+q] = 2*beta_jj.
// Survivor predicate symmetric in (i,l) => row[i] = ascending partner list of i.
// off[s][i] = #entries of row[i] with partner < 64*s (s in [0,32]); off[32][i] = count.
__global__ __launch_bounds__(256) void k_prepA(const float* __restrict__ beta,
                                               const float* __restrict__ alpha,
                                               const float* __restrict__ x,
                                               __half* __restrict__ Wg,
                                               int* __restrict__ off,
                                               unsigned short* __restrict__ idx) {
    const int tid = threadIdx.x;
    if (blockIdx.x < PREP_BLOCKS) {
        const int xb = blockIdx.x & 31, yb = blockIdx.x >> 5;   // 32 x 10
        const int tx = tid & 63, ty = tid >> 6;
        if (yb < 9) {
            __shared__ float t[64][65];
            const int l0 = xb * 64, ja0 = yb * 64;
            for (int r = ty; r < 64; r += 4) {
                int ja = ja0 + r, l = l0 + tx;
                if (ja < JA && l < NN) t[r][tx] = 2.0f * beta[(size_t)ja * NN + l];
            }
            __syncthreads();
            for (int r = ty; r < 64; r += 4) {
                int l = l0 + r, ja = ja0 + tx;
                if (l < NN && ja < JA) {
                    int g = ja / 144, pos = ja % 144;
                    Wg[((size_t)g * NN + l) * GROWH + pos] = __float2half(t[tx][r]);
                }
            }
        } else {
            int l = xb * 64 + (tid & 63);
            int g = tid >> 6;                 // 0..3
            if (l < NN) {
                __half* w = Wg + ((size_t)g * NN + l) * GROWH;
                #pragma unroll
                for (int q = 0; q < 6; ++q) {
                    int j = g * 6 + q;
                    w[HA_OFF + q] = __float2half(alpha[(size_t)j * NN + l]);
                    w[HD_OFF + q] = __float2half(2.0f * beta[(size_t)(j * DD + j) * NN + l]);
                }
            }
        }
    } else {
        const int pa = blockIdx.x - PREP_BLOCKS;       // 0..499
        const int wave = tid >> 6, lane = tid & 63;
        const int l = pa * 4 + wave;                   // 0..1999 (row owner)
        float xl[DD];
        {
            const float* xr = x + (size_t)l * DD;
            #pragma unroll
            for (int k = 0; k < DD; ++k) xl[k] = xr[k];
        }
        unsigned short* row = idx + (size_t)l * IDXCAP;
        int base = 0;
        for (int c = 0; c < 32; ++c) {                 // slab s = c (64 i's each)
            if (lane == 0) off[(size_t)c * NN + l] = base;
            int i = c * 64 + lane;
            bool valid = i < NN;
            int ic = valid ? i : 0;
            const float4* xv = reinterpret_cast<const float4*>(x + (size_t)ic * DD);
            float S = 0.f, m2 = 0.f;
            #pragma unroll
            for (int q = 0; q < 6; ++q) {
                float4 v = xv[q];
                float d0 = v.x - xl[4*q+0], d1 = v.y - xl[4*q+1];
                float d2 = v.z - xl[4*q+2], d3 = v.w - xl[4*q+3];
                d0 *= d0; d1 *= d1; d2 *= d2; d3 *= d3;
                S += (d0 + d1) + (d2 + d3);
                m2 = fmaxf(m2, fmaxf(fmaxf(d0, d1), fmaxf(d2, d3)));
            }
            bool pred = valid && (S - m2 <= THRESH);
            unsigned long long mask = __ballot(pred);
            if (pred) {
                int rank = __popcll(mask & ((1ull << lane) - 1ull));
                row[base + rank] = (unsigned short)i;
            }
            base += __popcll(mask);
        }
        if (lane == 0) off[(size_t)32 * NN + l] = base;
    }
}

// ================= pass B: i-major register accumulation, slab + parity split ==========
// Block (ib, s, g, p): thread i = ib*256+tid accumulates entries e = e0+p, e0+p+2, ...
// of row[i] restricted to slab s. No barriers, no RMW, bit-deterministic.
template <int J0>
__device__ __forceinline__ void passB_body(const float* __restrict__ x,
                                           const __half* __restrict__ Wg,
                                           const int* __restrict__ off,
                                           const unsigned short* __restrict__ idx,
                                           float* __restrict__ part,
                                           int i, int s, int p) {
    constexpr int g = J0 / 6;
    const int ic = i < NN ? i : 0;

    float xi[DD];
    {
        const float4* xr = reinterpret_cast<const float4*>(x + (size_t)ic * DD);
        #pragma unroll
        for (int q = 0; q < 6; ++q) {
            float4 v = xr[q];
            xi[4*q+0] = v.x; xi[4*q+1] = v.y; xi[4*q+2] = v.z; xi[4*q+3] = v.w;
        }
    }

    int e0 = 0, e1 = 0;
    if (i < NN) {
        e0 = off[(size_t)s * NN + i];
        e1 = off[(size_t)(s + 1) * NN + i];
    }
    const unsigned short* row = idx + (size_t)i * IDXCAP;

    float acc[6];
    #pragma unroll
    for (int q = 0; q < 6; ++q) acc[q] = 0.0f;

    #pragma unroll 1
    for (int e = e0 + p; e < e1; e += 2) {
        const int l = row[e];
        const __half* __restrict__ wrow = Wg + ((size_t)g * NN + l) * GROWH;
        const float4* __restrict__ xv = reinterpret_cast<const float4*>(x + (size_t)l * DD);

        float diff[DD];
        float negS = 0.f;
        #pragma unroll
        for (int q = 0; q < 6; ++q) {
            float4 vv = xv[q];
            float d0 = xi[4*q+0] - vv.x, d1 = xi[4*q+1] - vv.y;
            float d2 = xi[4*q+2] - vv.z, d3 = xi[4*q+3] - vv.w;
            diff[4*q+0] = d0; diff[4*q+1] = d1;
            diff[4*q+2] = d2; diff[4*q+3] = d3;
            negS = fmaf(-d0, d0, negS); negS = fmaf(-d1, d1, negS);
            negS = fmaf(-d2, d2, negS); negS = fmaf(-d3, d3, negS);
        }

        #pragma unroll
        for (int q = 0; q < 6; ++q) {
            float dj = diff[J0 + q];                         // compile-time index
            float K = __expf(fmaf(dj, dj, negS));            // exp(diff_j^2 - S)
            const __half2* b2 = reinterpret_cast<const __half2*>(wrow + q * 24);
            float t0 = 0.f, t1 = 0.f, t2 = 0.f, t3 = 0.f;
            #pragma unroll
            for (int k = 0; k < 6; ++k) {
                float2 b01 = __half22float2(b2[2*k]);
                float2 b23 = __half22float2(b2[2*k+1]);
                t0 = fmaf(b01.x, diff[4*k+0], t0);
                t1 = fmaf(b01.y, diff[4*k+1], t1);
                t2 = fmaf(b23.x, diff[4*k+2], t2);
                t3 = fmaf(b23.y, diff[4*k+3], t3);
            }
            float t = (t0 + t1) + (t2 + t3);
            t = fmaf(-__half2float(wrow[HD_OFF + q]), dj, t);   // drop a==j
            acc[q] += K * (__half2float(wrow[HA_OFF + q]) + t);
        }
    }

    if (i < NN) {
        const int sl = (s * 4 + g) * 2 + p;
        float* pp = part + ((size_t)sl * NN + i) * 6;
        #pragma unroll
        for (int q = 0; q < 6; ++q) pp[q] = acc[q];
    }
}

__global__ __launch_bounds__(256) void k_passB(const float* __restrict__ x,
                                               const __half* __restrict__ Wg,
                                               const int* __restrict__ off,
                                               const unsigned short* __restrict__ idx,
                                               float* __restrict__ part) {
    const int bid = blockIdx.x;                // 2048 blocks
    const int s  = bid & 31;                   // slab in low bits -> XCD L2 locality
    const int p  = (bid >> 5) & 1;
    const int g  = (bid >> 6) & 3;
    const int ib = bid >> 8;                   // 0..7
    const int i  = ib * 256 + threadIdx.x;     // 0..2047 (guarded)
    switch (g) {
        case 0:  passB_body<0 >(x, Wg, off, idx, part, i, s, p); break;
        case 1:  passB_body<6 >(x, Wg, off, idx, part, i, s, p); break;
        case 2:  passB_body<12>(x, Wg, off, idx, part, i, s, p); break;
        default: passB_body<18>(x, Wg, off, idx, part, i, s, p); break;
    }
}

// ---- pass C: out[i][j] = sum_{s,p} part[(s*4 + j/6)*2 + p][i][j%6]
__global__ __launch_bounds__(256) void k_passC(const float* __restrict__ part,
                                               float* __restrict__ out) {
    int m = blockIdx.x * 256 + threadIdx.x;
    if (m >= NN * DD) return;
    int i = m / DD, j = m - i * DD;
    int g = j / 6, q = j - g * 6;
    float a = 0.f;
    #pragma unroll 4
    for (int s = 0; s < NS; ++s) {
        a += part[(((size_t)(s * 4 + g) * 2 + 0) * NN + i) * 6 + q];
        a += part[(((size_t)(s * 4 + g) * 2 + 1) * NN + i) * 6 + q];
    }
    out[m] = a;
}

// ================= dense fallback (never taken in practice; fp16 Wg) =================
template <int J0>
__device__ __forceinline__ void run_j6(const float* __restrict__ x,
                                       const __half* __restrict__ Wg,
                                       float* __restrict__ part,
                                       const float (&xi)[DD],
                                       int i, int lb, int l0, int l1) {
    constexpr int g = J0 / 6;
    float acc[6];
    #pragma unroll
    for (int q = 0; q < 6; ++q) acc[q] = 0.0f;
    #pragma unroll 1
    for (int l = l0; l < l1; ++l) {
        const __half* __restrict__ wrow = Wg + ((size_t)g * NN + l) * GROWH;
        const float* __restrict__ xl = x + (size_t)l * DD;
        float diff[DD]; float negS = 0.0f;
        #pragma unroll
        for (int k = 0; k < DD; ++k) {
            float d = xi[k] - xl[k];
            diff[k] = d; negS = fmaf(-d, d, negS);
        }
        #pragma unroll
        for (int q = 0; q < 6; ++q) {
            float dj = diff[J0 + q];
            float K = __expf(fmaf(dj, dj, negS));
            const __half2* b2 = reinterpret_cast<const __half2*>(wrow + q * 24);
            float t0=0.f,t1=0.f,t2=0.f,t3=0.f;
            #pragma unroll
            for (int k = 0; k < 6; ++k) {
                float2 b01 = __half22float2(b2[2*k]);
                float2 b23 = __half22float2(b2[2*k+1]);
                t0 = fmaf(b01.x, diff[4*k+0], t0);
                t1 = fmaf(b01.y, diff[4*k+1], t1);
                t2 = fmaf(b23.x, diff[4*k+2], t2);
                t3 = fmaf(b23.y, diff[4*k+3], t3);
            }
            float t = (t0+t1)+(t2+t3);
            t = fmaf(-__half2float(wrow[HD_OFF + q]), dj, t);
            acc[q] = fmaf(K, __half2float(wrow[HA_OFF + q]) + t, acc[q]);
        }
    }
    if (i < NN) {
        #pragma unroll
        for (int q = 0; q < 6; ++q)
            part[((size_t)lb * DD + (J0+q)) * NN + i] = acc[q];
    }
}

__global__ __launch_bounds__(256, 4) void k_pass1_js(const float* __restrict__ x,
                                                     const __half* __restrict__ Wg,
                                                     float* __restrict__ part,
                                                     int lch) {
    const int tid  = threadIdx.x;
    const int wave = tid >> 6, lane = tid & 63;
    const int i  = blockIdx.x * 64 + lane;
    const int ic = i < NN ? i : NN - 1;
    const int lb = blockIdx.y;
    float xi[DD];
    {
        const float4* xr = reinterpret_cast<const float4*>(x + (size_t)ic * DD);
        #pragma unroll
        for (int q = 0; q < DD/4; ++q) {
            float4 v = xr[q];
            xi[4*q+0]=v.x; xi[4*q+1]=v.y; xi[4*q+2]=v.z; xi[4*q+3]=v.w;
        }
    }
    const int l0 = lb * lch;
    int l1 = l0 + lch; if (l1 > NN) l1 = NN;
    if      (wave == 0) run_j6<0 >(x, Wg, part, xi, i, lb, l0, l1);
    else if (wave == 1) run_j6<6 >(x, Wg, part, xi, i, lb, l0, l1);
    else if (wave == 2) run_j6<12>(x, Wg, part, xi, i, lb, l0, l1);
    else                run_j6<18>(x, Wg, part, xi, i, lb, l0, l1);
}

__global__ __launch_bounds__(256) void k_pass2t(const float* __restrict__ part,
                                                float* __restrict__ out, int lblk) {
    int m = blockIdx.x * 256 + threadIdx.x;
    if (m >= NN * DD) return;
    float s = 0.0f;
    for (int b = 0; b < lblk; ++b)
        s += part[(size_t)b * (NN * DD) + m];
    int j = m / NN, i = m - j * NN;
    out[(size_t)i * DD + j] = s;
}
// ================= end fallback =================

extern "C" void kernel_launch(void* const* d_in, const int* in_sizes, int n_in,
                              void* d_out, int out_size, void* d_ws, size_t ws_size,
                              hipStream_t stream) {
    const float* x     = (const float*)d_in[0];   // [2000, 24]
    const float* alpha = (const float*)d_in[1];   // [24, 2000]
    const float* beta  = (const float*)d_in[2];   // [24, 24, 2000]
    float* out = (float*)d_out;                   // [2000, 24]

    const size_t WBYTES    = (size_t)4 * NN * GROWH * 2;           // 2,560,000
    const size_t OFF_OFF   = WBYTES;
    const size_t OFFBYTES  = (size_t)33 * NN * 4;                  // 264,000
    const size_t IDX_OFF   = OFF_OFF + OFFBYTES;                   // 2,824,000
    const size_t IDXBYTES  = (size_t)NN * IDXCAP * 2;              // 8,192,000
    const size_t PART_OFF  = IDX_OFF + IDXBYTES;                   // 11,016,000
    const size_t PARTBYTES = (size_t)NS * 4 * 2 * NN * 6 * 4;      // 12,288,000
    const size_t NEED = PART_OFF + PARTBYTES;                      // ~23.3 MB

    __half* Wg = (__half*)d_ws;

    if (ws_size >= NEED) {
        int* off = (int*)((char*)d_ws + OFF_OFF);
        unsigned short* idx = (unsigned short*)((char*)d_ws + IDX_OFF);
        float* part = (float*)((char*)d_ws + PART_OFF);

        k_prepA<<<PREP_BLOCKS + 500, 256, 0, stream>>>(beta, alpha, x, Wg, off, idx);
        k_passB<<<8 * NS * 4 * 2, 256, 0, stream>>>(x, Wg, off, idx, part);
        k_passC<<<(NN * DD + 255) / 256, 256, 0, stream>>>(part, out);
    } else {
        // dense fallback (unlikely: ws proven >= 53 MB in earlier rounds)
        const size_t SLAB = (size_t)NN * DD * 4;
        float* part = (float*)((char*)d_ws + IDX_OFF);
        int lblk = 32;
        while (lblk > 1 && IDX_OFF + (size_t)lblk * SLAB > ws_size) lblk >>= 1;
        int lch = (NN + lblk - 1) / lblk;
        int* off = (int*)((char*)d_ws + OFF_OFF);
        unsigned short* dummy = (unsigned short*)((char*)d_ws + OFF_OFF);
        k_prepA<<<PREP_BLOCKS, 256, 0, stream>>>(beta, alpha, x, Wg, off, dummy);
        k_pass1_js<<<dim3(32, lblk), 256, 0, stream>>>(x, Wg, part, lch);
        k_pass2t<<<(NN * DD + 255) / 256, 256, 0, stream>>>(part, out, lblk);
    }
}

// Round 10
// 63.389 us; speedup vs baseline: 2.2266x; 1.0644x over previous
//
#include <hip/hip_runtime.h>
#include <hip/hip_bf16.h>
#include <hip/hip_fp16.h>

#define NN 2000
#define DD 24
#define JA 576
#define GROWH 160             // halves per (g,l) row: 144 (2*beta) + 6 alpha + 6 (2*diag) + 4 pad
#define HA_OFF 144
#define HD_OFF 150
#define IDXCAP 2048           // >= NN, rows can never overflow
#define THRESH 16.0f          // keep pair if S - max_j diff_j^2 <= THRESH
#define PREP_BLOCKS 320       // 32 x 10
#define PSPLIT 32             // contiguous chunk split of each i's list

// ================= merged prep (fp16 Wg build) + passA (survivor lists) =================
// Wg[g][l][160h]: [q*24+a] = 2*beta[6g+q][a][l] (fp16); [144+q] = alpha; [150+q] = 2*beta_jj.
// Survivor predicate symmetric in (i,l) => row[i] = ascending partner list of i; cnt[i].
__global__ __launch_bounds__(256) void k_prepA(const float* __restrict__ beta,
                                               const float* __restrict__ alpha,
                                               const float* __restrict__ x,
                                               __half* __restrict__ Wg,
                                               int* __restrict__ cnt,
                                               unsigned short* __restrict__ idx) {
    const int tid = threadIdx.x;
    if (blockIdx.x < PREP_BLOCKS) {
        const int xb = blockIdx.x & 31, yb = blockIdx.x >> 5;   // 32 x 10
        const int tx = tid & 63, ty = tid >> 6;
        if (yb < 9) {
            __shared__ float t[64][65];
            const int l0 = xb * 64, ja0 = yb * 64;
            for (int r = ty; r < 64; r += 4) {
                int ja = ja0 + r, l = l0 + tx;
                if (ja < JA && l < NN) t[r][tx] = 2.0f * beta[(size_t)ja * NN + l];
            }
            __syncthreads();
            for (int r = ty; r < 64; r += 4) {
                int l = l0 + r, ja = ja0 + tx;
                if (l < NN && ja < JA) {
                    int g = ja / 144, pos = ja % 144;
                    Wg[((size_t)g * NN + l) * GROWH + pos] = __float2half(t[tx][r]);
                }
            }
        } else {
            int l = xb * 64 + (tid & 63);
            int g = tid >> 6;                 // 0..3
            if (l < NN) {
                __half* w = Wg + ((size_t)g * NN + l) * GROWH;
                #pragma unroll
                for (int q = 0; q < 6; ++q) {
                    int j = g * 6 + q;
                    w[HA_OFF + q] = __float2half(alpha[(size_t)j * NN + l]);
                    w[HD_OFF + q] = __float2half(2.0f * beta[(size_t)(j * DD + j) * NN + l]);
                }
            }
        }
    } else {
        const int pa = blockIdx.x - PREP_BLOCKS;       // 0..499
        const int wave = tid >> 6, lane = tid & 63;
        const int l = pa * 4 + wave;                   // 0..1999 (row owner)
        float xl[DD];
        {
            const float* xr = x + (size_t)l * DD;
            #pragma unroll
            for (int k = 0; k < DD; ++k) xl[k] = xr[k];
        }
        unsigned short* row = idx + (size_t)l * IDXCAP;
        int base = 0;
        for (int c = 0; c < 32; ++c) {
            int i = c * 64 + lane;
            bool valid = i < NN;
            int ic = valid ? i : 0;
            const float4* xv = reinterpret_cast<const float4*>(x + (size_t)ic * DD);
            float S = 0.f, m2 = 0.f;
            #pragma unroll
            for (int q = 0; q < 6; ++q) {
                float4 v = xv[q];
                float d0 = v.x - xl[4*q+0], d1 = v.y - xl[4*q+1];
                float d2 = v.z - xl[4*q+2], d3 = v.w - xl[4*q+3];
                d0 *= d0; d1 *= d1; d2 *= d2; d3 *= d3;
                S += (d0 + d1) + (d2 + d3);
                m2 = fmaxf(m2, fmaxf(fmaxf(d0, d1), fmaxf(d2, d3)));
            }
            bool pred = valid && (S - m2 <= THRESH);
            unsigned long long mask = __ballot(pred);
            if (pred) {
                int rank = __popcll(mask & ((1ull << lane) - 1ull));
                row[base + rank] = (unsigned short)i;
            }
            base += __popcll(mask);
        }
        if (lane == 0) cnt[l] = base;
    }
}

// ================= sort: stable counting sort of i by count bucket (c>>4, 32 buckets) ====
// One block, 256 threads, thread t owns i in [8t, 8t+8). Deterministic (stable by i).
__global__ __launch_bounds__(256) void k_sort(const int* __restrict__ cnt,
                                              int* __restrict__ order) {
    __shared__ int lcnt[256][32];
    __shared__ int tot[32];
    __shared__ int base[33];
    const int t = threadIdx.x;
    #pragma unroll
    for (int b = 0; b < 32; ++b) lcnt[t][b] = 0;
    __syncthreads();
    #pragma unroll
    for (int k = 0; k < 8; ++k) {
        int i = t * 8 + k;
        if (i < NN) {
            int b = cnt[i] >> 4; b = b > 31 ? 31 : b;
            ++lcnt[t][b];
        }
    }
    __syncthreads();
    if (t < 32) {                       // prefix over threads for bucket t
        int run = 0;
        for (int tt = 0; tt < 256; ++tt) {
            int v = lcnt[tt][t];
            lcnt[tt][t] = run;
            run += v;
        }
        tot[t] = run;
    }
    __syncthreads();
    if (t == 0) {
        base[0] = 0;
        for (int b = 0; b < 32; ++b) base[b + 1] = base[b] + tot[b];
    }
    __syncthreads();
    #pragma unroll
    for (int k = 0; k < 8; ++k) {
        int i = t * 8 + k;
        if (i < NN) {
            int b = cnt[i] >> 4; b = b > 31 ? 31 : b;
            order[base[b] + lcnt[t][b]] = i;
            ++lcnt[t][b];
        }
    }
}

// ================= pass B: i-major, rank-sorted lanes, exact chunk split ==============
// Block (ib, g, p): thread rank = ib*256+tid -> i = order[rank]; entries
// [p*c/PSPLIT, (p+1)*c/PSPLIT) of row[i]. Exact per-thread work, no barriers, no RMW,
// bit-deterministic (ascending e per thread).
template <int J0>
__device__ __forceinline__ void passB_body(const float* __restrict__ x,
                                           const __half* __restrict__ Wg,
                                           const int* __restrict__ cnt,
                                           const int* __restrict__ order,
                                           const unsigned short* __restrict__ idx,
                                           float* __restrict__ part,
                                           int rank, int p) {
    constexpr int g = J0 / 6;
    const bool valid = rank < NN;
    const int i = valid ? order[rank] : 0;

    float xi[DD];
    {
        const float4* xr = reinterpret_cast<const float4*>(x + (size_t)i * DD);
        #pragma unroll
        for (int q = 0; q < 6; ++q) {
            float4 v = xr[q];
            xi[4*q+0] = v.x; xi[4*q+1] = v.y; xi[4*q+2] = v.z; xi[4*q+3] = v.w;
        }
    }

    const int c  = valid ? cnt[i] : 0;
    const int e0 = (p * c) >> 5;            // p*c/PSPLIT
    const int e1 = ((p + 1) * c) >> 5;
    const unsigned short* row = idx + (size_t)i * IDXCAP;

    float acc[6];
    #pragma unroll
    for (int q = 0; q < 6; ++q) acc[q] = 0.0f;

    #pragma unroll 1
    for (int e = e0; e < e1; ++e) {
        const int l = row[e];
        const __half* __restrict__ wrow = Wg + ((size_t)g * NN + l) * GROWH;
        const float4* __restrict__ xv = reinterpret_cast<const float4*>(x + (size_t)l * DD);

        float diff[DD];
        float negS = 0.f;
        #pragma unroll
        for (int q = 0; q < 6; ++q) {
            float4 vv = xv[q];
            float d0 = xi[4*q+0] - vv.x, d1 = xi[4*q+1] - vv.y;
            float d2 = xi[4*q+2] - vv.z, d3 = xi[4*q+3] - vv.w;
            diff[4*q+0] = d0; diff[4*q+1] = d1;
            diff[4*q+2] = d2; diff[4*q+3] = d3;
            negS = fmaf(-d0, d0, negS); negS = fmaf(-d1, d1, negS);
            negS = fmaf(-d2, d2, negS); negS = fmaf(-d3, d3, negS);
        }

        #pragma unroll
        for (int q = 0; q < 6; ++q) {
            float dj = diff[J0 + q];                         // compile-time index
            float K = __expf(fmaf(dj, dj, negS));            // exp(diff_j^2 - S)
            const __half2* b2 = reinterpret_cast<const __half2*>(wrow + q * 24);
            float t0 = 0.f, t1 = 0.f, t2 = 0.f, t3 = 0.f;
            #pragma unroll
            for (int k = 0; k < 6; ++k) {
                float2 b01 = __half22float2(b2[2*k]);
                float2 b23 = __half22float2(b2[2*k+1]);
                t0 = fmaf(b01.x, diff[4*k+0], t0);
                t1 = fmaf(b01.y, diff[4*k+1], t1);
                t2 = fmaf(b23.x, diff[4*k+2], t2);
                t3 = fmaf(b23.y, diff[4*k+3], t3);
            }
            float t = (t0 + t1) + (t2 + t3);
            t = fmaf(-__half2float(wrow[HD_OFF + q]), dj, t);   // drop a==j
            acc[q] += K * (__half2float(wrow[HA_OFF + q]) + t);
        }
    }

    if (valid) {
        float* pp = part + ((size_t)(p * 4 + g) * NN + i) * 6;
        #pragma unroll
        for (int q = 0; q < 6; ++q) pp[q] = acc[q];
    }
}

__global__ __launch_bounds__(256) void k_passB(const float* __restrict__ x,
                                               const __half* __restrict__ Wg,
                                               const int* __restrict__ cnt,
                                               const int* __restrict__ order,
                                               const unsigned short* __restrict__ idx,
                                               float* __restrict__ part) {
    const int bid = blockIdx.x;                // 1024 blocks = 8 (ib) x 4 (g) x 32 (p)
    const int p   = bid & 31;
    const int g   = (bid >> 5) & 3;
    const int ib  = bid >> 7;                  // 0..7
    const int rank = ib * 256 + threadIdx.x;   // 0..2047 (guarded)
    switch (g) {
        case 0:  passB_body<0 >(x, Wg, cnt, order, idx, part, rank, p); break;
        case 1:  passB_body<6 >(x, Wg, cnt, order, idx, part, rank, p); break;
        case 2:  passB_body<12>(x, Wg, cnt, order, idx, part, rank, p); break;
        default: passB_body<18>(x, Wg, cnt, order, idx, part, rank, p); break;
    }
}

// ---- pass C: out[i][j] = sum_p part[(p*4 + j/6)][i][j%6]
__global__ __launch_bounds__(256) void k_passC(const float* __restrict__ part,
                                               float* __restrict__ out) {
    int m = blockIdx.x * 256 + threadIdx.x;
    if (m >= NN * DD) return;
    int i = m / DD, j = m - i * DD;
    int g = j / 6, q = j - g * 6;
    float a = 0.f;
    #pragma unroll 4
    for (int p = 0; p < PSPLIT; ++p)
        a += part[((size_t)(p * 4 + g) * NN + i) * 6 + q];
    out[m] = a;
}

// ================= dense fallback (never taken in practice; fp16 Wg) =================
template <int J0>
__device__ __forceinline__ void run_j6(const float* __restrict__ x,
                                       const __half* __restrict__ Wg,
                                       float* __restrict__ part,
                                       const float (&xi)[DD],
                                       int i, int lb, int l0, int l1) {
    constexpr int g = J0 / 6;
    float acc[6];
    #pragma unroll
    for (int q = 0; q < 6; ++q) acc[q] = 0.0f;
    #pragma unroll 1
    for (int l = l0; l < l1; ++l) {
        const __half* __restrict__ wrow = Wg + ((size_t)g * NN + l) * GROWH;
        const float* __restrict__ xl = x + (size_t)l * DD;
        float diff[DD]; float negS = 0.0f;
        #pragma unroll
        for (int k = 0; k < DD; ++k) {
            float d = xi[k] - xl[k];
            diff[k] = d; negS = fmaf(-d, d, negS);
        }
        #pragma unroll
        for (int q = 0; q < 6; ++q) {
            float dj = diff[J0 + q];
            float K = __expf(fmaf(dj, dj, negS));
            const __half2* b2 = reinterpret_cast<const __half2*>(wrow + q * 24);
            float t0=0.f,t1=0.f,t2=0.f,t3=0.f;
            #pragma unroll
            for (int k = 0; k < 6; ++k) {
                float2 b01 = __half22float2(b2[2*k]);
                float2 b23 = __half22float2(b2[2*k+1]);
                t0 = fmaf(b01.x, diff[4*k+0], t0);
                t1 = fmaf(b01.y, diff[4*k+1], t1);
                t2 = fmaf(b23.x, diff[4*k+2], t2);
                t3 = fmaf(b23.y, diff[4*k+3], t3);
            }
            float t = (t0+t1)+(t2+t3);
            t = fmaf(-__half2float(wrow[HD_OFF + q]), dj, t);
            acc[q] = fmaf(K, __half2float(wrow[HA_OFF + q]) + t, acc[q]);
        }
    }
    if (i < NN) {
        #pragma unroll
        for (int q = 0; q < 6; ++q)
            part[((size_t)lb * DD + (J0+q)) * NN + i] = acc[q];
    }
}

__global__ __launch_bounds__(256, 4) void k_pass1_js(const float* __restrict__ x,
                                                     const __half* __restrict__ Wg,
                                                     float* __restrict__ part,
                                                     int lch) {
    const int tid  = threadIdx.x;
    const int wave = tid >> 6, lane = tid & 63;
    const int i  = blockIdx.x * 64 + lane;
    const int ic = i < NN ? i : NN - 1;
    const int lb = blockIdx.y;
    float xi[DD];
    {
        const float4* xr = reinterpret_cast<const float4*>(x + (size_t)ic * DD);
        #pragma unroll
        for (int q = 0; q < DD/4; ++q) {
            float4 v = xr[q];
            xi[4*q+0]=v.x; xi[4*q+1]=v.y; xi[4*q+2]=v.z; xi[4*q+3]=v.w;
        }
    }
    const int l0 = lb * lch;
    int l1 = l0 + lch; if (l1 > NN) l1 = NN;
    if      (wave == 0) run_j6<0 >(x, Wg, part, xi, i, lb, l0, l1);
    else if (wave == 1) run_j6<6 >(x, Wg, part, xi, i, lb, l0, l1);
    else if (wave == 2) run_j6<12>(x, Wg, part, xi, i, lb, l0, l1);
    else                run_j6<18>(x, Wg, part, xi, i, lb, l0, l1);
}

__global__ __launch_bounds__(256) void k_pass2t(const float* __restrict__ part,
                                                float* __restrict__ out, int lblk) {
    int m = blockIdx.x * 256 + threadIdx.x;
    if (m >= NN * DD) return;
    float s = 0.0f;
    for (int b = 0; b < lblk; ++b)
        s += part[(size_t)b * (NN * DD) + m];
    int j = m / NN, i = m - j * NN;
    out[(size_t)i * DD + j] = s;
}
// ================= end fallback =================

extern "C" void kernel_launch(void* const* d_in, const int* in_sizes, int n_in,
                              void* d_out, int out_size, void* d_ws, size_t ws_size,
                              hipStream_t stream) {
    const float* x     = (const float*)d_in[0];   // [2000, 24]
    const float* alpha = (const float*)d_in[1];   // [24, 2000]
    const float* beta  = (const float*)d_in[2];   // [24, 24, 2000]
    float* out = (float*)d_out;                   // [2000, 24]

    const size_t WBYTES    = (size_t)4 * NN * GROWH * 2;           // 2,560,000
    const size_t CNT_OFF   = WBYTES;
    const size_t ORD_OFF   = CNT_OFF + 8192;
    const size_t IDX_OFF   = ORD_OFF + 8192;
    const size_t IDXBYTES  = (size_t)NN * IDXCAP * 2;              // 8,192,000
    const size_t PART_OFF  = IDX_OFF + IDXBYTES;
    const size_t PARTBYTES = (size_t)PSPLIT * 4 * NN * 6 * 4;      // 6,144,000
    const size_t NEED = PART_OFF + PARTBYTES;                      // ~16.9 MB

    __half* Wg = (__half*)d_ws;

    if (ws_size >= NEED) {
        int* cnt   = (int*)((char*)d_ws + CNT_OFF);
        int* order = (int*)((char*)d_ws + ORD_OFF);
        unsigned short* idx = (unsigned short*)((char*)d_ws + IDX_OFF);
        float* part = (float*)((char*)d_ws + PART_OFF);

        k_prepA<<<PREP_BLOCKS + 500, 256, 0, stream>>>(beta, alpha, x, Wg, cnt, idx);
        k_sort<<<1, 256, 0, stream>>>(cnt, order);
        k_passB<<<8 * 4 * PSPLIT, 256, 0, stream>>>(x, Wg, cnt, order, idx, part);
        k_passC<<<(NN * DD + 255) / 256, 256, 0, stream>>>(part, out);
    } else {
        // dense fallback (unlikely: ws proven >= 53 MB in earlier rounds)
        const size_t SLAB = (size_t)NN * DD * 4;
        float* part = (float*)((char*)d_ws + IDX_OFF);
        int lblk = 32;
        while (lblk > 1 && IDX_OFF + (size_t)lblk * SLAB > ws_size) lblk >>= 1;
        int lch = (NN + lblk - 1) / lblk;
        int* cnt = (int*)((char*)d_ws + CNT_OFF);
        unsigned short* dummy = (unsigned short*)((char*)d_ws + CNT_OFF);
        k_prepA<<<PREP_BLOCKS, 256, 0, stream>>>(beta, alpha, x, Wg, cnt, dummy);
        k_pass1_js<<<dim3(32, lblk), 256, 0, stream>>>(x, Wg, part, lch);
        k_pass2t<<<(NN * DD + 255) / 256, 256, 0, stream>>>(part, out, lblk);
    }
}